// Round 6
// baseline (1062.685 us; speedup 1.0000x reference)
//
#include <hip/hip_runtime.h>
#include <stdint.h>

#define D_DIM 128
#define K_DIM 1024
#define BM 64
#define N_TOTAL 262144
#define TAU 0.1f
#define MAXF 16384

typedef __attribute__((ext_vector_type(8))) short short8;
typedef __attribute__((ext_vector_type(4))) float f32x4;

__device__ __forceinline__ unsigned short f2bf(float f) {
    union { float f; uint32_t u; } v; v.f = f;
    uint32_t r = v.u + 0x7fffu + ((v.u >> 16) & 1u);
    return (unsigned short)(r >> 16);
}
__device__ __forceinline__ float bf2f(unsigned short h) {
    union { float f; uint32_t u; } v; v.u = ((uint32_t)h) << 16;
    return v.f;
}

// ---------------------------------------------------------------------------
// prep: C[1024][128] fp32 -> B-frag bf16 hi/lo + c2[k] (32-lane shfl reduce)
// ---------------------------------------------------------------------------
__global__ __launch_bounds__(256) void prep_kernel(const float* __restrict__ C,
                                                   unsigned short* __restrict__ Cfrag,
                                                   float* __restrict__ c2) {
    int g = blockIdx.x * 256 + threadIdx.x;   // 0..32767
    int col = g >> 5;
    int dq = g & 31;
    float4 v = ((const float4*)C)[g];
    unsigned short h0 = f2bf(v.x), h1 = f2bf(v.y), h2 = f2bf(v.z), h3 = f2bf(v.w);
    unsigned short l0 = f2bf(v.x - bf2f(h0)), l1 = f2bf(v.y - bf2f(h1));
    unsigned short l2 = f2bf(v.z - bf2f(h2)), l3 = f2bf(v.w - bf2f(h3));
    int ntg = col >> 4;
    int cl = col & 15;
    int d0 = dq << 2;
    int ds = d0 >> 5;
    int lane = (((d0 >> 3) & 3) << 4) | cl;
    int jb = d0 & 7;
    size_t idx = (((size_t)(ntg * 4 + ds) * 64 + lane) * 8 + jb);
    uint2 hv = make_uint2((uint32_t)h0 | ((uint32_t)h1 << 16),
                          (uint32_t)h2 | ((uint32_t)h3 << 16));
    uint2 lv = make_uint2((uint32_t)l0 | ((uint32_t)l1 << 16),
                          (uint32_t)l2 | ((uint32_t)l3 << 16));
    *(uint2*)&Cfrag[idx] = hv;
    *(uint2*)&Cfrag[131072 + idx] = lv;

    float p = fmaf(v.x, v.x, fmaf(v.y, v.y, fmaf(v.z, v.z, v.w * v.w)));
    #pragma unroll
    for (int off = 1; off < 32; off <<= 1) p += __shfl_xor(p, off);
    if ((threadIdx.x & 31) == 0) c2[col] = p;
}

// ---------------------------------------------------------------------------
// fused: bf16x3 MFMA distances + packed-key argmin/2nd-min + sum exp(-d) + loss
// block 256 thr = 4 waves; wave tile 32 rows x 64 cols per kc chunk.
// key = (bits(d2) & ~1023) | k  (monotone in d2; ties -> lower k).
// __launch_bounds__(256,2): 256-reg budget (any lower splits arch cap < demand
// and spills -- R3/R5 evidence). Software-pipelined: epilogue of chunk kc-1
// overlaps MFMA + B-loads of chunk kc via double-buffered accumulators.
// ---------------------------------------------------------------------------
__global__ __launch_bounds__(256, 2) void fused_mfma_kernel(
        const float* __restrict__ E,
        const unsigned short* __restrict__ Cfrag,
        const float* __restrict__ c2g,
        float* __restrict__ out,
        int* __restrict__ fcnt,
        int* __restrict__ flist)
{
    __shared__ unsigned short Elds[32 * 528];   // 33 KB frag-layout E hi/lo
    __shared__ float c2s[K_DIM];                // 4 KB
    __shared__ float e2s[BM];                   // 256 B
    __shared__ uint32_t mrgk[BM * 2];
    __shared__ uint32_t mrgm[BM * 2];
    __shared__ float    mrgs[BM * 2];

    const int tid = threadIdx.x;
    const int lane = tid & 63;
    const int w = tid >> 6;
    const int Rh = w >> 1;       // row half (32 rows each)
    const int Nh = w & 1;        // col half of each 128-col chunk
    const int q = lane >> 4;
    const int mcol = lane & 15;
    const int row0 = blockIdx.x * BM;

    if (tid < BM) e2s[tid] = 0.f;
    for (int i = tid; i < K_DIM; i += 256) c2s[i] = c2g[i];
    __syncthreads();

    // ---- stage E tile: fp32 -> bf16 hi/lo frag layout; accumulate e2 ----
    {
        const float4* E4 = (const float4*)(E + (size_t)row0 * D_DIM);
        #pragma unroll
        for (int it = 0; it < 8; ++it) {
            int chunk = it * 256 + tid;      // 0..2047
            int r = chunk >> 5;              // row 0..63
            int dq = chunk & 31;
            float4 v = E4[chunk];
            float p = fmaf(v.x, v.x, fmaf(v.y, v.y, fmaf(v.z, v.z, v.w * v.w)));
            atomicAdd(&e2s[r], p);
            unsigned short h0 = f2bf(v.x), h1 = f2bf(v.y), h2 = f2bf(v.z), h3 = f2bf(v.w);
            unsigned short l0 = f2bf(v.x - bf2f(h0)), l1 = f2bf(v.y - bf2f(h1));
            unsigned short l2 = f2bf(v.z - bf2f(h2)), l3 = f2bf(v.w - bf2f(h3));
            int d0 = dq << 2;
            int mt = r >> 4;
            int ds = d0 >> 5;
            int lane_slot = (((d0 >> 3) & 3) << 4) | (r & 15);
            int jb = d0 & 7;
            int segh = (mt * 4 + ds) * 528 + lane_slot * 8 + jb;
            uint2 hv = make_uint2((uint32_t)h0 | ((uint32_t)h1 << 16),
                                  (uint32_t)h2 | ((uint32_t)h3 << 16));
            uint2 lv = make_uint2((uint32_t)l0 | ((uint32_t)l1 << 16),
                                  (uint32_t)l2 | ((uint32_t)l3 << 16));
            *(uint2*)&Elds[segh] = hv;
            *(uint2*)&Elds[16 * 528 + segh] = lv;
        }
    }
    __syncthreads();

    float e2r[8];
    #pragma unroll
    for (int s = 0; s < 8; ++s)
        e2r[s] = e2s[(Rh * 2 + (s >> 2)) * 16 + q * 4 + (s & 3)];

    uint32_t k1v[8], m2v[8];
    float sv[8];
    #pragma unroll
    for (int s = 0; s < 8; ++s) { k1v[s] = 0xFFFFFFFFu; m2v[s] = 0xFFFFFFFFu; sv[s] = 0.f; }

    const short8* Bfrag = (const short8*)Cfrag;   // hi at [0], lo at +16384 (short8 units)

    // epilogue of one k-chunk's accumulators (independent VALU chain -- the
    // scheduler overlaps it with the next chunk's B-loads + MFMA ladder)
    auto epilogue = [&](f32x4 (&acc)[2][4], int kc) {
        #pragma unroll
        for (int ni = 0; ni < 4; ++ni) {
            int kidx = kc * 128 + Nh * 64 + ni * 16 + mcol;
            float c2v = c2s[kidx];
            #pragma unroll
            for (int mi = 0; mi < 2; ++mi) {
                #pragma unroll
                for (int r = 0; r < 4; ++r) {
                    int s = mi * 4 + r;
                    float d2 = fmaf(-2.f, acc[mi][ni][r], e2r[s] + c2v);
                    d2 = fmaxf(d2, 0.f);
                    uint32_t key = (__float_as_uint(d2) & 0xFFFFFC00u) | (uint32_t)kidx;
                    float dist = __builtin_amdgcn_sqrtf(d2);
                    sv[s] += __expf(-dist);
                    uint32_t k1 = k1v[s];
                    m2v[s] = min(m2v[s], max(k1, key));
                    k1v[s] = min(k1, key);
                }
            }
        }
    };

    f32x4 acc[2][2][4];   // double-buffered accumulators (64 AGPRs)

    #pragma unroll 1
    for (int kc = 0; kc < 8; ++kc) {
        const int p = kc & 1;
        #pragma unroll
        for (int i = 0; i < 2; ++i)
            #pragma unroll
            for (int j = 0; j < 4; ++j)
                acc[p][i][j] = (f32x4){0.f, 0.f, 0.f, 0.f};

        #pragma unroll
        for (int ds = 0; ds < 4; ++ds) {
            short8 ah[2], al[2];
            #pragma unroll
            for (int mi = 0; mi < 2; ++mi) {
                int seg = ((Rh * 2 + mi) * 4 + ds) * 528 + lane * 8;
                ah[mi] = *(const short8*)&Elds[seg];
                al[mi] = *(const short8*)&Elds[16 * 528 + seg];
            }
            #pragma unroll
            for (int ni = 0; ni < 4; ++ni) {
                int ntg = kc * 8 + Nh * 4 + ni;
                size_t bidx = ((size_t)ntg * 4 + ds) * 64 + lane;
                short8 bh = Bfrag[bidx];
                short8 bl = Bfrag[16384 + bidx];
                #pragma unroll
                for (int mi = 0; mi < 2; ++mi) {
                    acc[p][mi][ni] = __builtin_amdgcn_mfma_f32_16x16x32_bf16(al[mi], bh, acc[p][mi][ni], 0, 0, 0);
                    acc[p][mi][ni] = __builtin_amdgcn_mfma_f32_16x16x32_bf16(ah[mi], bl, acc[p][mi][ni], 0, 0, 0);
                    acc[p][mi][ni] = __builtin_amdgcn_mfma_f32_16x16x32_bf16(ah[mi], bh, acc[p][mi][ni], 0, 0, 0);
                }
            }
        }
        // pipelined epilogue: reduce the PREVIOUS chunk while this chunk's
        // MFMAs/B-loads are in flight
        if (kc > 0) epilogue(acc[1 - p], kc - 1);
    }
    epilogue(acc[1], 7);   // drain: kc=7 landed in buffer p=1

    // ---- merge across the 16 lanes sharing q (cols) ----
    #pragma unroll
    for (int s = 0; s < 8; ++s) {
        #pragma unroll
        for (int off = 1; off < 16; off <<= 1) {
            uint32_t ok1 = __shfl_xor(k1v[s], off);
            uint32_t om2 = __shfl_xor(m2v[s], off);
            float osv = __shfl_xor(sv[s], off);
            m2v[s] = min(min(m2v[s], om2), max(k1v[s], ok1));
            k1v[s] = min(k1v[s], ok1);
            sv[s] += osv;
        }
    }
    if (mcol == 0) {
        #pragma unroll
        for (int s = 0; s < 8; ++s) {
            int row = (Rh * 2 + (s >> 2)) * 16 + q * 4 + (s & 3);
            mrgk[row * 2 + Nh] = k1v[s];
            mrgm[row * 2 + Nh] = m2v[s];
            mrgs[row * 2 + Nh] = sv[s];
        }
    }
    __syncthreads();

    // ---- final per-row merge across the two col-halves; outputs ----
    if (tid < BM) {
        uint32_t ka = mrgk[tid * 2 + 0], kb = mrgk[tid * 2 + 1];
        uint32_t ma = mrgm[tid * 2 + 0], mb = mrgm[tid * 2 + 1];
        float ss = mrgs[tid * 2 + 0] + mrgs[tid * 2 + 1];
        uint32_t k1 = min(ka, kb);
        uint32_t m2 = min(min(ma, mb), max(ka, kb));
        float m1q = __uint_as_float(k1 & 0xFFFFFC00u);
        float m2q = __uint_as_float(m2 & 0xFFFFFC00u);
        int i1 = (int)(k1 & 1023u);
        float lossr = logf(ss) + sqrtf(m1q);   // lse - target
        out[1 + row0 + tid] = (float)i1;
        if (m2q - m1q < TAU) {
            int idx = atomicAdd(fcnt, 1);
            if (idx < MAXF) flist[idx] = row0 + tid;
        }
        float v = lossr;
        #pragma unroll
        for (int off = 32; off > 0; off >>= 1) v += __shfl_down(v, off);
        if (tid == 0) atomicAdd(out, v * (1.0f / (float)N_TOTAL));
    }
}

// ---------------------------------------------------------------------------
// refine: exact fp32 recompute (precise sqrt, first-occurrence argmin) for
// flagged rows. 4 rows per block. UNCHANGED (rounding-validated vs np).
// ---------------------------------------------------------------------------
__global__ void refine_kernel(const float* __restrict__ E,
                              const float* __restrict__ C,
                              const float* __restrict__ c2g,
                              const int* __restrict__ fcnt,
                              const int* __restrict__ flist,
                              float* __restrict__ out) {
    int cnt = *fcnt;
    if (cnt > MAXF) cnt = MAXF;
    int base = blockIdx.x * 4;
    if (base >= cnt) return;
    int nr = cnt - base;
    if (nr > 4) nr = 4;

    __shared__ float Er[4][D_DIM];
    __shared__ float e2r_[4];
    __shared__ float2 red[256];

    const int tid = threadIdx.x;
    int rows[4];
    #pragma unroll
    for (int r = 0; r < 4; ++r) {
        int rr = r < nr ? r : (nr - 1);
        rows[r] = flist[base + rr];
    }
    for (int i = tid; i < 4 * D_DIM; i += 256) {
        int rr = i >> 7;
        int dd = i & 127;
        Er[rr][dd] = E[(size_t)rows[rr] * D_DIM + dd];
    }
    __syncthreads();
    if (tid < 4) {
        float s = 0.f;
        for (int d = 0; d < D_DIM; ++d) s = fmaf(Er[tid][d], Er[tid][d], s);
        e2r_[tid] = s;
    }
    __syncthreads();

    float bm[4] = {1e30f, 1e30f, 1e30f, 1e30f};
    float bk[4] = {0.f, 0.f, 0.f, 0.f};
    for (int ii = 0; ii < 4; ++ii) {
        int k = ii * 256 + tid;
        float dot0 = 0.f, dot1 = 0.f, dot2 = 0.f, dot3 = 0.f;
        const float4* C4 = (const float4*)(C + (size_t)k * D_DIM);
        for (int dq = 0; dq < 32; ++dq) {
            float4 cv = C4[dq];
            int d0 = dq * 4;
            dot0 = fmaf(Er[0][d0], cv.x, fmaf(Er[0][d0 + 1], cv.y, fmaf(Er[0][d0 + 2], cv.z, fmaf(Er[0][d0 + 3], cv.w, dot0))));
            dot1 = fmaf(Er[1][d0], cv.x, fmaf(Er[1][d0 + 1], cv.y, fmaf(Er[1][d0 + 2], cv.z, fmaf(Er[1][d0 + 3], cv.w, dot1))));
            dot2 = fmaf(Er[2][d0], cv.x, fmaf(Er[2][d0 + 1], cv.y, fmaf(Er[2][d0 + 2], cv.z, fmaf(Er[2][d0 + 3], cv.w, dot2))));
            dot3 = fmaf(Er[3][d0], cv.x, fmaf(Er[3][d0 + 1], cv.y, fmaf(Er[3][d0 + 2], cv.z, fmaf(Er[3][d0 + 3], cv.w, dot3))));
        }
        float c2v = c2g[k];
        float dd[4];
        dd[0] = dot0; dd[1] = dot1; dd[2] = dot2; dd[3] = dot3;
        #pragma unroll
        for (int r = 0; r < 4; ++r) {
            float d2 = (e2r_[r] + c2v) - 2.f * dd[r];
            float dist = sqrtf(fmaxf(d2, 0.f));
            if (dist < bm[r]) { bm[r] = dist; bk[r] = (float)k; }
        }
    }
    for (int r = 0; r < nr; ++r) {
        red[tid] = make_float2(bm[r], bk[r]);
        __syncthreads();
        for (int off = 128; off > 0; off >>= 1) {
            if (tid < off) {
                float2 o = red[tid + off];
                float2 m = red[tid];
                if (o.x < m.x || (o.x == m.x && o.y < m.y)) red[tid] = o;
            }
            __syncthreads();
        }
        if (tid == 0) out[1 + rows[r]] = red[0].y;
        __syncthreads();
    }
}

extern "C" void kernel_launch(void* const* d_in, const int* in_sizes, int n_in,
                              void* d_out, int out_size, void* d_ws, size_t ws_size,
                              hipStream_t stream) {
    const float* E = (const float*)d_in[0];
    const float* C = (const float*)d_in[1];
    float* out = (float*)d_out;

    unsigned short* Cfrag = (unsigned short*)d_ws;                 // 512 KB
    float* c2 = (float*)((char*)d_ws + 524288);                    // 4 KB
    int* fcnt = (int*)((char*)d_ws + 524288 + 4096);               // 4 B
    int* flist = fcnt + 1;                                         // MAXF ints

    hipMemsetAsync(d_out, 0, sizeof(float), stream);   // loss accumulator
    hipMemsetAsync(fcnt, 0, sizeof(int), stream);      // refinement counter

    prep_kernel<<<dim3(128), dim3(256), 0, stream>>>(C, Cfrag, c2);
    fused_mfma_kernel<<<dim3(N_TOTAL / BM), dim3(256), 0, stream>>>(E, Cfrag, c2, out, fcnt, flist);
    refine_kernel<<<dim3(MAXF / 4), dim3(256), 0, stream>>>(E, C, c2, fcnt, flist, out);
}

// Round 7
// 500.902 us; speedup vs baseline: 2.1215x; 2.1215x over previous
//
#include <hip/hip_runtime.h>
#include <stdint.h>

#define D_DIM 128
#define K_DIM 1024
#define BM 64
#define N_TOTAL 262144
#define TAU 0.1f
#define MAXF 16384

typedef __attribute__((ext_vector_type(8))) short short8;
typedef __attribute__((ext_vector_type(4))) float f32x4;

__device__ __forceinline__ unsigned short f2bf(float f) {
    union { float f; uint32_t u; } v; v.f = f;
    uint32_t r = v.u + 0x7fffu + ((v.u >> 16) & 1u);
    return (unsigned short)(r >> 16);
}
__device__ __forceinline__ float bf2f(unsigned short h) {
    union { float f; uint32_t u; } v; v.u = ((uint32_t)h) << 16;
    return v.f;
}

// ---------------------------------------------------------------------------
// prep: C[1024][128] fp32 -> B-frag bf16 hi/lo + c2[k]; also zeroes the loss
// accumulator and the refine counter (folds the two memset dispatches).
// ---------------------------------------------------------------------------
__global__ __launch_bounds__(256) void prep_kernel(const float* __restrict__ C,
                                                   unsigned short* __restrict__ Cfrag,
                                                   float* __restrict__ c2,
                                                   float* __restrict__ out,
                                                   int* __restrict__ fcnt) {
    int g = blockIdx.x * 256 + threadIdx.x;   // 0..32767
    if (g == 0) { out[0] = 0.f; *fcnt = 0; }
    int col = g >> 5;
    int dq = g & 31;
    float4 v = ((const float4*)C)[g];
    unsigned short h0 = f2bf(v.x), h1 = f2bf(v.y), h2 = f2bf(v.z), h3 = f2bf(v.w);
    unsigned short l0 = f2bf(v.x - bf2f(h0)), l1 = f2bf(v.y - bf2f(h1));
    unsigned short l2 = f2bf(v.z - bf2f(h2)), l3 = f2bf(v.w - bf2f(h3));
    int ntg = col >> 4;
    int cl = col & 15;
    int d0 = dq << 2;
    int ds = d0 >> 5;
    int lane = (((d0 >> 3) & 3) << 4) | cl;
    int jb = d0 & 7;
    size_t idx = (((size_t)(ntg * 4 + ds) * 64 + lane) * 8 + jb);
    uint2 hv = make_uint2((uint32_t)h0 | ((uint32_t)h1 << 16),
                          (uint32_t)h2 | ((uint32_t)h3 << 16));
    uint2 lv = make_uint2((uint32_t)l0 | ((uint32_t)l1 << 16),
                          (uint32_t)l2 | ((uint32_t)l3 << 16));
    *(uint2*)&Cfrag[idx] = hv;
    *(uint2*)&Cfrag[131072 + idx] = lv;

    float p = fmaf(v.x, v.x, fmaf(v.y, v.y, fmaf(v.z, v.z, v.w * v.w)));
    #pragma unroll
    for (int off = 1; off < 32; off <<= 1) p += __shfl_xor(p, off);
    if ((threadIdx.x & 31) == 0) c2[col] = p;
}

// ---------------------------------------------------------------------------
// fused: bf16x3 MFMA distances + packed-key argmin/2nd-min + sum exp(-d) + loss
// block 256 thr = 4 waves; wave tile 32 rows x 64 cols per kc chunk.
// key = (bits(d2) & ~1023) | k  (monotone in d2; ties -> lower k).
// __launch_bounds__(256,2): 256-reg budget (lower splits arch cap < demand and
// spills -- R3/R5/R6 evidence). vs R4: (a) ni-outer/ds-inner accumulation so
// each acc[ni] completes early -> its epilogue overlaps the next ni's MFMAs in
// one basic block (R4's ds-outer order made ALL epilogue depend on tail MFMAs);
// (b) A-fragments loaded ONCE into regs (constant across kc) -> no LDS in loop.
// ---------------------------------------------------------------------------
__global__ __launch_bounds__(256, 2) void fused_mfma_kernel(
        const float* __restrict__ E,
        const unsigned short* __restrict__ Cfrag,
        const float* __restrict__ c2g,
        float* __restrict__ out,
        int* __restrict__ fcnt,
        int* __restrict__ flist)
{
    __shared__ unsigned short Elds[32 * 528];   // 33 KB frag-layout E hi/lo
    __shared__ float c2s[K_DIM];                // 4 KB
    __shared__ float e2s[BM];                   // 256 B
    __shared__ uint32_t mrgk[BM * 2];
    __shared__ uint32_t mrgm[BM * 2];
    __shared__ float    mrgs[BM * 2];

    const int tid = threadIdx.x;
    const int lane = tid & 63;
    const int w = tid >> 6;
    const int Rh = w >> 1;       // row half (32 rows each)
    const int Nh = w & 1;        // col half of each 128-col chunk
    const int q = lane >> 4;
    const int mcol = lane & 15;
    const int row0 = blockIdx.x * BM;

    if (tid < BM) e2s[tid] = 0.f;
    for (int i = tid; i < K_DIM; i += 256) c2s[i] = c2g[i];
    __syncthreads();

    // ---- stage E tile: fp32 -> bf16 hi/lo frag layout; accumulate e2 ----
    {
        const float4* E4 = (const float4*)(E + (size_t)row0 * D_DIM);
        #pragma unroll
        for (int it = 0; it < 8; ++it) {
            int chunk = it * 256 + tid;      // 0..2047
            int r = chunk >> 5;              // row 0..63
            int dq = chunk & 31;
            float4 v = E4[chunk];
            float p = fmaf(v.x, v.x, fmaf(v.y, v.y, fmaf(v.z, v.z, v.w * v.w)));
            atomicAdd(&e2s[r], p);
            unsigned short h0 = f2bf(v.x), h1 = f2bf(v.y), h2 = f2bf(v.z), h3 = f2bf(v.w);
            unsigned short l0 = f2bf(v.x - bf2f(h0)), l1 = f2bf(v.y - bf2f(h1));
            unsigned short l2 = f2bf(v.z - bf2f(h2)), l3 = f2bf(v.w - bf2f(h3));
            int d0 = dq << 2;
            int mt = r >> 4;
            int ds = d0 >> 5;
            int lane_slot = (((d0 >> 3) & 3) << 4) | (r & 15);
            int jb = d0 & 7;
            int segh = (mt * 4 + ds) * 528 + lane_slot * 8 + jb;
            uint2 hv = make_uint2((uint32_t)h0 | ((uint32_t)h1 << 16),
                                  (uint32_t)h2 | ((uint32_t)h3 << 16));
            uint2 lv = make_uint2((uint32_t)l0 | ((uint32_t)l1 << 16),
                                  (uint32_t)l2 | ((uint32_t)l3 << 16));
            *(uint2*)&Elds[segh] = hv;
            *(uint2*)&Elds[16 * 528 + segh] = lv;
        }
    }
    __syncthreads();

    // ---- load ALL A fragments once (constant across kc): 64 VGPRs ----
    short8 Ah[2][4], Al[2][4];
    #pragma unroll
    for (int mi = 0; mi < 2; ++mi)
        #pragma unroll
        for (int ds = 0; ds < 4; ++ds) {
            int seg = ((Rh * 2 + mi) * 4 + ds) * 528 + lane * 8;
            Ah[mi][ds] = *(const short8*)&Elds[seg];
            Al[mi][ds] = *(const short8*)&Elds[16 * 528 + seg];
        }

    float e2r[8];
    #pragma unroll
    for (int s = 0; s < 8; ++s)
        e2r[s] = e2s[(Rh * 2 + (s >> 2)) * 16 + q * 4 + (s & 3)];

    uint32_t k1v[8], m2v[8];
    float sv[8];
    #pragma unroll
    for (int s = 0; s < 8; ++s) { k1v[s] = 0xFFFFFFFFu; m2v[s] = 0xFFFFFFFFu; sv[s] = 0.f; }

    const short8* Bfrag = (const short8*)Cfrag;   // hi at [0], lo at +16384 (short8 units)

    // epilogue for ONE (kc, ni) column-group: 8 elements/lane
    auto epi = [&](f32x4 (&a)[2], int kidx) {
        float c2v = c2s[kidx];
        #pragma unroll
        for (int mi = 0; mi < 2; ++mi) {
            #pragma unroll
            for (int r = 0; r < 4; ++r) {
                int s = mi * 4 + r;
                float d2 = fmaf(-2.f, a[mi][r], e2r[s] + c2v);
                d2 = fmaxf(d2, 0.f);
                uint32_t key = (__float_as_uint(d2) & 0xFFFFFC00u) | (uint32_t)kidx;
                float dist = __builtin_amdgcn_sqrtf(d2);
                sv[s] += __expf(-dist);
                uint32_t k1 = k1v[s];
                m2v[s] = min(m2v[s], max(k1, key));
                k1v[s] = min(k1, key);
            }
        }
    };

    #pragma unroll 1
    for (int kc = 0; kc < 8; ++kc) {
        f32x4 acc[4][2];   // [ni][mi]
        #pragma unroll
        for (int ni = 0; ni < 4; ++ni) {
            int ntg = kc * 8 + Nh * 4 + ni;
            short8 bh[4], bl[4];
            #pragma unroll
            for (int ds = 0; ds < 4; ++ds) {
                size_t bidx = ((size_t)ntg * 4 + ds) * 64 + lane;
                bh[ds] = Bfrag[bidx];
                bl[ds] = Bfrag[16384 + bidx];
            }
            #pragma unroll
            for (int mi = 0; mi < 2; ++mi) acc[ni][mi] = (f32x4){0.f, 0.f, 0.f, 0.f};
            #pragma unroll
            for (int ds = 0; ds < 4; ++ds)
                #pragma unroll
                for (int mi = 0; mi < 2; ++mi) {
                    acc[ni][mi] = __builtin_amdgcn_mfma_f32_16x16x32_bf16(Al[mi][ds], bh[ds], acc[ni][mi], 0, 0, 0);
                    acc[ni][mi] = __builtin_amdgcn_mfma_f32_16x16x32_bf16(Ah[mi][ds], bl[ds], acc[ni][mi], 0, 0, 0);
                    acc[ni][mi] = __builtin_amdgcn_mfma_f32_16x16x32_bf16(Ah[mi][ds], bh[ds], acc[ni][mi], 0, 0, 0);
                }
            // overlap: previous ni's epilogue is independent of this ni's MFMAs
            if (ni > 0) epi(acc[ni - 1], kc * 128 + Nh * 64 + (ni - 1) * 16 + mcol);
        }
        epi(acc[3], kc * 128 + Nh * 64 + 3 * 16 + mcol);
    }

    // ---- merge across the 16 lanes sharing q (cols) ----
    #pragma unroll
    for (int s = 0; s < 8; ++s) {
        #pragma unroll
        for (int off = 1; off < 16; off <<= 1) {
            uint32_t ok1 = __shfl_xor(k1v[s], off);
            uint32_t om2 = __shfl_xor(m2v[s], off);
            float osv = __shfl_xor(sv[s], off);
            m2v[s] = min(min(m2v[s], om2), max(k1v[s], ok1));
            k1v[s] = min(k1v[s], ok1);
            sv[s] += osv;
        }
    }
    if (mcol == 0) {
        #pragma unroll
        for (int s = 0; s < 8; ++s) {
            int row = (Rh * 2 + (s >> 2)) * 16 + q * 4 + (s & 3);
            mrgk[row * 2 + Nh] = k1v[s];
            mrgm[row * 2 + Nh] = m2v[s];
            mrgs[row * 2 + Nh] = sv[s];
        }
    }
    __syncthreads();

    // ---- final per-row merge across the two col-halves; outputs ----
    if (tid < BM) {
        uint32_t ka = mrgk[tid * 2 + 0], kb = mrgk[tid * 2 + 1];
        uint32_t ma = mrgm[tid * 2 + 0], mb = mrgm[tid * 2 + 1];
        float ss = mrgs[tid * 2 + 0] + mrgs[tid * 2 + 1];
        uint32_t k1 = min(ka, kb);
        uint32_t m2 = min(min(ma, mb), max(ka, kb));
        float m1q = __uint_as_float(k1 & 0xFFFFFC00u);
        float m2q = __uint_as_float(m2 & 0xFFFFFC00u);
        int i1 = (int)(k1 & 1023u);
        float lossr = logf(ss) + sqrtf(m1q);   // lse - target
        out[1 + row0 + tid] = (float)i1;
        if (m2q - m1q < TAU) {
            int idx = atomicAdd(fcnt, 1);
            if (idx < MAXF) flist[idx] = row0 + tid;
        }
        float v = lossr;
        #pragma unroll
        for (int off = 32; off > 0; off >>= 1) v += __shfl_down(v, off);
        if (tid == 0) atomicAdd(out, v * (1.0f / (float)N_TOTAL));
    }
}

// ---------------------------------------------------------------------------
// refine: exact fp32 recompute (precise sqrt, first-occurrence argmin) for
// flagged rows. 4 rows per block. UNCHANGED (rounding-validated vs np).
// ---------------------------------------------------------------------------
__global__ void refine_kernel(const float* __restrict__ E,
                              const float* __restrict__ C,
                              const float* __restrict__ c2g,
                              const int* __restrict__ fcnt,
                              const int* __restrict__ flist,
                              float* __restrict__ out) {
    int cnt = *fcnt;
    if (cnt > MAXF) cnt = MAXF;
    int base = blockIdx.x * 4;
    if (base >= cnt) return;
    int nr = cnt - base;
    if (nr > 4) nr = 4;

    __shared__ float Er[4][D_DIM];
    __shared__ float e2r_[4];
    __shared__ float2 red[256];

    const int tid = threadIdx.x;
    int rows[4];
    #pragma unroll
    for (int r = 0; r < 4; ++r) {
        int rr = r < nr ? r : (nr - 1);
        rows[r] = flist[base + rr];
    }
    for (int i = tid; i < 4 * D_DIM; i += 256) {
        int rr = i >> 7;
        int dd = i & 127;
        Er[rr][dd] = E[(size_t)rows[rr] * D_DIM + dd];
    }
    __syncthreads();
    if (tid < 4) {
        float s = 0.f;
        for (int d = 0; d < D_DIM; ++d) s = fmaf(Er[tid][d], Er[tid][d], s);
        e2r_[tid] = s;
    }
    __syncthreads();

    float bm[4] = {1e30f, 1e30f, 1e30f, 1e30f};
    float bk[4] = {0.f, 0.f, 0.f, 0.f};
    for (int ii = 0; ii < 4; ++ii) {
        int k = ii * 256 + tid;
        float dot0 = 0.f, dot1 = 0.f, dot2 = 0.f, dot3 = 0.f;
        const float4* C4 = (const float4*)(C + (size_t)k * D_DIM);
        for (int dq = 0; dq < 32; ++dq) {
            float4 cv = C4[dq];
            int d0 = dq * 4;
            dot0 = fmaf(Er[0][d0], cv.x, fmaf(Er[0][d0 + 1], cv.y, fmaf(Er[0][d0 + 2], cv.z, fmaf(Er[0][d0 + 3], cv.w, dot0))));
            dot1 = fmaf(Er[1][d0], cv.x, fmaf(Er[1][d0 + 1], cv.y, fmaf(Er[1][d0 + 2], cv.z, fmaf(Er[1][d0 + 3], cv.w, dot1))));
            dot2 = fmaf(Er[2][d0], cv.x, fmaf(Er[2][d0 + 1], cv.y, fmaf(Er[2][d0 + 2], cv.z, fmaf(Er[2][d0 + 3], cv.w, dot2))));
            dot3 = fmaf(Er[3][d0], cv.x, fmaf(Er[3][d0 + 1], cv.y, fmaf(Er[3][d0 + 2], cv.z, fmaf(Er[3][d0 + 3], cv.w, dot3))));
        }
        float c2v = c2g[k];
        float dd[4];
        dd[0] = dot0; dd[1] = dot1; dd[2] = dot2; dd[3] = dot3;
        #pragma unroll
        for (int r = 0; r < 4; ++r) {
            float d2 = (e2r_[r] + c2v) - 2.f * dd[r];
            float dist = sqrtf(fmaxf(d2, 0.f));
            if (dist < bm[r]) { bm[r] = dist; bk[r] = (float)k; }
        }
    }
    for (int r = 0; r < nr; ++r) {
        red[tid] = make_float2(bm[r], bk[r]);
        __syncthreads();
        for (int off = 128; off > 0; off >>= 1) {
            if (tid < off) {
                float2 o = red[tid + off];
                float2 m = red[tid];
                if (o.x < m.x || (o.x == m.x && o.y < m.y)) red[tid] = o;
            }
            __syncthreads();
        }
        if (tid == 0) out[1 + rows[r]] = red[0].y;
        __syncthreads();
    }
}

extern "C" void kernel_launch(void* const* d_in, const int* in_sizes, int n_in,
                              void* d_out, int out_size, void* d_ws, size_t ws_size,
                              hipStream_t stream) {
    const float* E = (const float*)d_in[0];
    const float* C = (const float*)d_in[1];
    float* out = (float*)d_out;

    unsigned short* Cfrag = (unsigned short*)d_ws;                 // 512 KB
    float* c2 = (float*)((char*)d_ws + 524288);                    // 4 KB
    int* fcnt = (int*)((char*)d_ws + 524288 + 4096);               // 4 B
    int* flist = fcnt + 1;                                         // MAXF ints

    prep_kernel<<<dim3(128), dim3(256), 0, stream>>>(C, Cfrag, c2, out, fcnt);
    fused_mfma_kernel<<<dim3(N_TOTAL / BM), dim3(256), 0, stream>>>(E, Cfrag, c2, out, fcnt, flist);
    refine_kernel<<<dim3(MAXF / 4), dim3(256), 0, stream>>>(E, C, c2, fcnt, flist, out);
}